// Round 3
// baseline (305.367 us; speedup 1.0000x reference)
//
#include <hip/hip_runtime.h>

// DtN operator, M=64, N=32 RHS. One workgroup per RHS.
// Chebyshev(deg-8)-preconditioned CG in fp64 on the symmetrically scaled
// interior operator B = D^{-1/2} A D^{-1/2} (unit diagonal, spectrum in (0,2)).
// Row-contiguous ownership: thread t owns row t>>3, cols ((t&7)*8)..+7.
// LDS row stride padded to 65 doubles: bank = (2r+16c+2q)%32 -> 16 even banks,
// 4-way aliasing instead of the 32-way conflict of stride 64.

#define BLK 512
#define NBP 252
#define DEG 8        // matvecs per preconditioner apply = DEG-1
#define MAXOUT 150
#define LDP 65       // padded LDS row stride (doubles)

static __device__ __forceinline__ double hm(double x, double y) {
    double d = x + y;
    return d == 0.0 ? 0.0 : 2.0 * x * y / d;
}

// one-barrier block reduction: wave partials -> LDS -> replicated sum
static __device__ __forceinline__ double bred(double v, double* slot) {
    #pragma unroll
    for (int off = 32; off > 0; off >>= 1) v += __shfl_down(v, off, 64);
    if ((threadIdx.x & 63) == 0) slot[threadIdx.x >> 6] = v;
    __syncthreads();
    double s = 0.0;
    #pragma unroll
    for (int w = 0; w < 8; ++w) s += slot[w];
    return s;
}

// clockwise Dirichlet embedding (top, right, bottom rev, left rev)
static __device__ __forceinline__ double embed(const float* db, int i, int j) {
    if (i == 0 && j <= 62) return (double)db[j];
    if (j == 63 && i <= 62) return (double)db[63 + i];
    if (i == 63 && j >= 1)  return (double)db[189 - j];
    return (double)db[252 - i];   // j==0, i>=1
}

__global__ __launch_bounds__(BLK, 1) void dtn_cheb(const float* __restrict__ dbc,
                                                   const float* __restrict__ a,
                                                   float* __restrict__ out) {
    __shared__ double P[64 * LDP];
    __shared__ double Z0[64 * LDP];
    __shared__ double Z1[64 * LDP];
    __shared__ double redA[8], redB[8];

    const int t = threadIdx.x;
    const int row = t >> 3;
    const int cb  = (t & 7) << 3;
    const int gbase = (row << 6) + cb;   // global (stride-64) index for a[]
    const int base  = row * LDP + cb;    // padded LDS index
    const float* db = dbc + blockIdx.x * NBP;
    const bool irow = (row >= 1 && row <= 62);

    double cE[8], cW[8], cN[8], cS[8], sD[8];
    double y[8], r[8], z[8], dv[8], pw[8];

    // ---- init: raw harmonic-mean coefficients (h^-2 cancels), scale, u0 ----
    #pragma unroll
    for (int q = 0; q < 8; ++q) {
        const int gi = gbase + q;
        const int i = row, j = cb + q;
        double e = 0, w = 0, nn = 0, ss = 0, sv = 0;
        if (i > 0 && i < 63 && j > 0 && j < 63) {
            const double ac = (double)a[gi];
            e  = hm(ac, (double)a[gi + 1]);
            w  = hm((double)a[gi - 1], ac);
            nn = hm((double)a[gi - 64], ac);
            ss = hm(ac, (double)a[gi + 64]);
            sv = 1.0 / sqrt(e + w + nn + ss);
        }
        cE[q] = e; cW[q] = w; cN[q] = nn; cS[q] = ss; sD[q] = sv;
        double uv = 0.0;
        if (i == 0 || i == 63 || j == 0 || j == 63) uv = embed(db, i, j);
        P[base + q]  = uv;    // u0 (boundary data, interior 0)
        Z0[base + q] = sv;    // stage s for neighbor access
    }
    __syncthreads();

    // ---- g = s .* (A_raw u0) on interior; build scaled coefficients ----
    double g[8];
    #pragma unroll
    for (int q = 0; q < 8; ++q) g[q] = 0.0;
    if (irow) {
        #pragma unroll
        for (int q = 0; q < 8; ++q) {
            const int idx = base + q;
            const double uN = P[idx - LDP], uS = P[idx + LDP];
            const double uW = P[idx - 1],   uE = P[idx + 1];
            g[q] = sD[q] * (cE[q] * uE + cW[q] * uW + cN[q] * uN + cS[q] * uS);
            const double sN = Z0[idx - LDP], sS = Z0[idx + LDP];
            const double sW = Z0[idx - 1],   sE = Z0[idx + 1];
            cE[q] *= sD[q] * sE; cW[q] *= sD[q] * sW;
            cN[q] *= sD[q] * sN; cS[q] *= sD[q] * sS;
        }
    } else {
        #pragma unroll
        for (int q = 0; q < 8; ++q) { cE[q] = cW[q] = cN[q] = cS[q] = 0.0; }
    }
    __syncthreads();   // all reads of s (Z0) complete before Z0 is reused

    // ---- Chebyshev preconditioner: z ~= B^{-1} r, spectrum in [0.02, 2.0] ----
    const double thet = 0.5 * (2.0 + 0.02);
    const double delt = 0.5 * (2.0 - 0.02);
    const double sig  = thet / delt;
    const double invthet = 1.0 / thet;

    auto cheb = [&](const double* rr, double* zz) {
        double rho = 1.0 / sig;
        #pragma unroll
        for (int q = 0; q < 8; ++q) { dv[q] = rr[q] * invthet; zz[q] = dv[q]; Z1[base + q] = zz[q]; }
        int cur = 1;
        for (int k = 2; k <= DEG; ++k) {
            __syncthreads();   // zz writes visible; previous buffer reads done
            double* Zc = cur ? Z1 : Z0;
            double* Za = cur ? Z0 : Z1;
            double res[8];
            if (irow) {
                #pragma unroll
                for (int q = 0; q < 8; ++q) {
                    const int idx = base + q;
                    const double vN = Zc[idx - LDP], vS = Zc[idx + LDP];
                    const double vW = (q == 0) ? Zc[idx - 1] : zz[q - 1];
                    const double vE = (q == 7) ? Zc[idx + 1] : zz[q + 1];
                    const double Bz = zz[q] - (cE[q] * vE + cW[q] * vW + cN[q] * vN + cS[q] * vS);
                    res[q] = rr[q] - Bz;
                }
            } else {
                #pragma unroll
                for (int q = 0; q < 8; ++q) res[q] = 0.0;
            }
            const double rho1 = 1.0 / (2.0 * sig - rho);
            const double c1 = rho1 * rho, c2 = 2.0 * rho1 / delt;
            #pragma unroll
            for (int q = 0; q < 8; ++q) { dv[q] = c1 * dv[q] + c2 * res[q]; zz[q] += dv[q]; Za[base + q] = zz[q]; }
            rho = rho1; cur ^= 1;
        }
    };

    // ---- PCG on B y = g ----
    #pragma unroll
    for (int q = 0; q < 8; ++q) { y[q] = 0.0; r[q] = g[q]; }

    cheb(r, z);
    double rz_loc = 0.0;
    #pragma unroll
    for (int q = 0; q < 8; ++q) { pw[q] = z[q]; P[base + q] = z[q]; rz_loc += r[q] * z[q]; }
    double rz = bred(rz_loc, redB);
    const double stop = rz * 1e-11;

    for (int ot = 0; ot < MAXOUT && rz > stop; ++ot) {
        __syncthreads();   // P (p-vector) writes visible for stencil
        double w[8];
        double pap_loc = 0.0;
        if (irow) {
            #pragma unroll
            for (int q = 0; q < 8; ++q) {
                const int idx = base + q;
                const double vN = P[idx - LDP], vS = P[idx + LDP];
                const double vW = (q == 0) ? P[idx - 1] : pw[q - 1];
                const double vE = (q == 7) ? P[idx + 1] : pw[q + 1];
                w[q] = pw[q] - (cE[q] * vE + cW[q] * vW + cN[q] * vN + cS[q] * vS);
                pap_loc += pw[q] * w[q];
            }
        } else {
            #pragma unroll
            for (int q = 0; q < 8; ++q) w[q] = 0.0;
        }
        const double pap = bred(pap_loc, redA);
        if (!(pap > 0.0)) break;
        const double alpha = rz / pap;
        #pragma unroll
        for (int q = 0; q < 8; ++q) { y[q] += alpha * pw[q]; r[q] -= alpha * w[q]; }
        cheb(r, z);
        double rzn_loc = 0.0;
        #pragma unroll
        for (int q = 0; q < 8; ++q) rzn_loc += r[q] * z[q];
        const double rzn = bred(rzn_loc, redB);
        const double beta = rzn / rz;
        rz = rzn;
        if (rz > stop) {
            #pragma unroll
            for (int q = 0; q < 8; ++q) { pw[q] = z[q] + beta * pw[q]; P[base + q] = pw[q]; }
        }
    }

    // ---- final u = s .* y (interior), dbc on boundary; stage in P ----
    __syncthreads();
    #pragma unroll
    for (int q = 0; q < 8; ++q) {
        const int i = row, j = cb + q;
        double uv;
        if (i == 0 || i == 63 || j == 0 || j == 63) uv = embed(db, i, j);
        else uv = sD[q] * y[q];
        P[base + q] = uv;
    }
    __syncthreads();

    // ---- Neumann flux (clockwise) + de-mean; P uses padded stride LDP ----
    double v = 0.0;
    if (t < NBP) {
        const double Hi = 63.0;
        if (t == 0)        v = (double)a[0]  * 0.5 * ((P[0] - P[LDP]) + (P[0] - P[1])) * Hi;
        else if (t <= 62)  v = (double)a[t]  * (P[t] - P[LDP + t]) * Hi;
        else if (t == 63)  v = (double)a[63] * 0.5 * ((P[63] - P[LDP + 63]) + (P[63] - P[62])) * Hi;
        else if (t <= 125) { const int i = t - 63;
                             v = (double)a[(i<<6)+63] * (P[i*LDP+63] - P[i*LDP+62]) * Hi; }
        else if (t == 126) v = (double)a[4095] * 0.5 * ((P[63*LDP+63] - P[62*LDP+63]) + (P[63*LDP+63] - P[63*LDP+62])) * Hi;
        else if (t <= 188) { const int j = 189 - t;
                             v = (double)a[4032+j] * (P[63*LDP+j] - P[62*LDP+j]) * Hi; }
        else if (t == 189) v = (double)a[4032] * 0.5 * ((P[63*LDP] - P[62*LDP]) + (P[63*LDP] - P[63*LDP+1])) * Hi;
        else               { const int i = 252 - t;
                             v = (double)a[i<<6] * (P[i*LDP] - P[i*LDP+1]) * Hi; }
    }
    const double tot = bred(v, redA);
    if (t < NBP) out[blockIdx.x * NBP + t] = (float)(v - tot * (1.0 / 252.0));
}

extern "C" void kernel_launch(void* const* d_in, const int* in_sizes, int n_in,
                              void* d_out, int out_size, void* d_ws, size_t ws_size,
                              hipStream_t stream) {
    const float* dbc = (const float*)d_in[0];   // (32, 252)
    const float* a   = (const float*)d_in[1];   // (64, 64)
    float* out = (float*)d_out;                 // (32, 252)
    dtn_cheb<<<dim3(32), dim3(BLK), 0, stream>>>(dbc, a, out);
}

// Round 4
// 94.045 us; speedup vs baseline: 3.2470x; 3.2470x over previous
//
#include <hip/hip_runtime.h>

// DtN operator, M=64, N=32 RHS. One workgroup per RHS.
// Chebyshev(deg-8)-preconditioned CG in fp32 (fp64 scalar accumulation) on the
// symmetrically scaled interior operator B = D^{-1/2} A D^{-1/2}.
// Thread t owns row t>>3, cols 8*(t&7)..+7. LDS rows stride 68 floats:
// 16B-aligned 8-float runs (float4 ds ops legal) and bank-group
// (r+2c+s)%8 uniform over all 8 groups -> b128 at bank floor, no conflicts.

#define BLK 512
#define NBP 252
#define DEG 8
#define MAXOUT 60
#define LDF 68

typedef float v4 __attribute__((ext_vector_type(4)));

static __device__ __forceinline__ float hmf(float x, float y) {
    float d = x + y;
    return d == 0.f ? 0.f : 2.f * x * y / d;
}

// one-barrier block reduction, fp64
static __device__ __forceinline__ double bred(double v, double* slot) {
    #pragma unroll
    for (int off = 32; off > 0; off >>= 1) v += __shfl_down(v, off, 64);
    if ((threadIdx.x & 63) == 0) slot[threadIdx.x >> 6] = v;
    __syncthreads();
    double s = 0.0;
    #pragma unroll
    for (int w = 0; w < 8; ++w) s += slot[w];
    return s;
}

// clockwise Dirichlet embedding (top, right, bottom rev, left rev)
static __device__ __forceinline__ float embedf(const float* db, int i, int j) {
    if (i == 0 && j <= 62) return db[j];
    if (j == 63 && i <= 62) return db[63 + i];
    if (i == 63 && j >= 1)  return db[189 - j];
    return db[252 - i];   // j==0, i>=1
}

__global__ __launch_bounds__(BLK, 1) void dtn_cheb(const float* __restrict__ dbc,
                                                   const float* __restrict__ a,
                                                   float* __restrict__ out) {
    __shared__ float P[64 * LDF];
    __shared__ float Z0[64 * LDF];
    __shared__ float Z1[64 * LDF];
    __shared__ double redA[8], redB[8];

    const int t = threadIdx.x;
    const int row = t >> 3;
    const int cb  = (t & 7) << 3;
    const int gbase = (row << 6) + cb;
    const int base  = row * LDF + cb;
    const float* db = dbc + blockIdx.x * NBP;
    const bool irow = (row >= 1 && row <= 62);

    // zero-fill (pads must be 0: edge reads hit them, x0 coefficients)
    for (int i = t; i < 64 * LDF; i += BLK) { P[i] = 0.f; Z0[i] = 0.f; Z1[i] = 0.f; }
    __syncthreads();

    float cE[8], cW[8], cN[8], cS[8], sD[8];
    float r8[8], y8[8], z8[8], dv8[8], pw8[8];

    // ---- coefficients (h^-2 cancels), diag scale s, u0 embed ----
    #pragma unroll
    for (int q = 0; q < 8; ++q) {
        const int gi = gbase + q;
        const int i = row, j = cb + q;
        float e = 0, w = 0, nn = 0, ss = 0, sv = 0;
        if (i > 0 && i < 63 && j > 0 && j < 63) {
            const float ac = a[gi];
            e  = hmf(ac, a[gi + 1]);
            w  = hmf(a[gi - 1], ac);
            nn = hmf(a[gi - 64], ac);
            ss = hmf(ac, a[gi + 64]);
            sv = 1.f / sqrtf(e + w + nn + ss);
        }
        cE[q] = e; cW[q] = w; cN[q] = nn; cS[q] = ss; sD[q] = sv;
        float uv = 0.f;
        if (i == 0 || i == 63 || j == 0 || j == 63) uv = embedf(db, i, j);
        P[base + q]  = uv;
        Z0[base + q] = sv;
        y8[q] = 0.f; r8[q] = 0.f;
    }
    __syncthreads();

    // ---- r0 = s .* (A_raw u0); scale coefficients by s_i * s_neighbor ----
    if (irow) {
        #pragma unroll
        for (int q = 0; q < 8; ++q) {
            const int idx = base + q;
            r8[q] = sD[q] * (cE[q] * P[idx + 1] + cW[q] * P[idx - 1] +
                             cN[q] * P[idx - LDF] + cS[q] * P[idx + LDF]);
            cE[q] *= sD[q] * Z0[idx + 1];
            cW[q] *= sD[q] * Z0[idx - 1];
            cN[q] *= sD[q] * Z0[idx - LDF];
            cS[q] *= sD[q] * Z0[idx + LDF];
        }
    } else {
        #pragma unroll
        for (int q = 0; q < 8; ++q) { cE[q] = cW[q] = cN[q] = cS[q] = 0.f; }
    }
    __syncthreads();   // Z0 (s) reads done before cheb reuses it

    // ---- Chebyshev preconditioner on [0.02, 2.0] ----
    const float thet = 1.01f, delt = 0.99f;
    const float sigc = thet / delt;
    const float invthet = 1.f / thet;

    auto cheb = [&](const float* rr, float* zz, float* dv) {
        float rho = 1.f / sigc;
        {
            v4 a0, a1;
            #pragma unroll
            for (int q = 0; q < 4; ++q) { dv[q] = rr[q] * invthet; zz[q] = dv[q]; a0[q] = dv[q]; }
            #pragma unroll
            for (int q = 4; q < 8; ++q) { dv[q] = rr[q] * invthet; zz[q] = dv[q]; a1[q - 4] = dv[q]; }
            *(v4*)&Z1[base] = a0; *(v4*)&Z1[base + 4] = a1;
        }
        int cur = 1;
        for (int k = 2; k <= DEG; ++k) {
            __syncthreads();
            const float* Zc = cur ? Z1 : Z0;
            float res[8];
            if (irow) {
                const v4 n0 = *(const v4*)&Zc[base - LDF], n1 = *(const v4*)&Zc[base - LDF + 4];
                const v4 s0 = *(const v4*)&Zc[base + LDF], s1 = *(const v4*)&Zc[base + LDF + 4];
                const float wv = Zc[base - 1], ev = Zc[base + 8];
                const float vN[8] = {n0[0],n0[1],n0[2],n0[3],n1[0],n1[1],n1[2],n1[3]};
                const float vS[8] = {s0[0],s0[1],s0[2],s0[3],s1[0],s1[1],s1[2],s1[3]};
                #pragma unroll
                for (int q = 0; q < 8; ++q) {
                    const float vW = (q == 0) ? wv : zz[q - 1];
                    const float vE = (q == 7) ? ev : zz[q + 1];
                    res[q] = rr[q] - (zz[q] - (cE[q] * vE + cW[q] * vW +
                                               cN[q] * vN[q] + cS[q] * vS[q]));
                }
            } else {
                #pragma unroll
                for (int q = 0; q < 8; ++q) res[q] = 0.f;
            }
            const float rho1 = 1.f / (2.f * sigc - rho);
            const float c1 = rho1 * rho, c2 = 2.f * rho1 / delt;
            v4 a0, a1;
            #pragma unroll
            for (int q = 0; q < 8; ++q) { dv[q] = c1 * dv[q] + c2 * res[q]; zz[q] += dv[q]; }
            #pragma unroll
            for (int q = 0; q < 4; ++q) a0[q] = zz[q];
            #pragma unroll
            for (int q = 0; q < 4; ++q) a1[q] = zz[q + 4];
            if (cur) { *(v4*)&Z0[base] = a0; *(v4*)&Z0[base + 4] = a1; }
            else     { *(v4*)&Z1[base] = a0; *(v4*)&Z1[base + 4] = a1; }
            rho = rho1; cur ^= 1;
        }
    };

    // ---- PCG on B y = r0 ----
    cheb(r8, z8, dv8);
    double rz_loc = 0.0;
    #pragma unroll
    for (int q = 0; q < 8; ++q) { pw8[q] = z8[q]; rz_loc += (double)r8[q] * z8[q]; }
    {
        v4 p0, p1;
        #pragma unroll
        for (int q = 0; q < 4; ++q) p0[q] = pw8[q];
        #pragma unroll
        for (int q = 0; q < 4; ++q) p1[q] = pw8[q + 4];
        *(v4*)&P[base] = p0; *(v4*)&P[base + 4] = p1;
    }
    double rz = bred(rz_loc, redB);
    const double stop = rz * 1e-8;
    int stg = 0;

    for (int ot = 0; ot < MAXOUT && rz > stop; ++ot) {
        __syncthreads();   // p writes visible
        float w8[8];
        double pap_loc = 0.0;
        if (irow) {
            const v4 n0 = *(const v4*)&P[base - LDF], n1 = *(const v4*)&P[base - LDF + 4];
            const v4 s0 = *(const v4*)&P[base + LDF], s1 = *(const v4*)&P[base + LDF + 4];
            const float wv = P[base - 1], ev = P[base + 8];
            const float vN[8] = {n0[0],n0[1],n0[2],n0[3],n1[0],n1[1],n1[2],n1[3]};
            const float vS[8] = {s0[0],s0[1],s0[2],s0[3],s1[0],s1[1],s1[2],s1[3]};
            #pragma unroll
            for (int q = 0; q < 8; ++q) {
                const float vW = (q == 0) ? wv : pw8[q - 1];
                const float vE = (q == 7) ? ev : pw8[q + 1];
                w8[q] = pw8[q] - (cE[q] * vE + cW[q] * vW + cN[q] * vN[q] + cS[q] * vS[q]);
                pap_loc += (double)pw8[q] * w8[q];
            }
        } else {
            #pragma unroll
            for (int q = 0; q < 8; ++q) w8[q] = 0.f;
        }
        const double pap = bred(pap_loc, redA);
        if (!(pap > 0.0)) break;
        const float alpha = (float)(rz / pap);
        #pragma unroll
        for (int q = 0; q < 8; ++q) { y8[q] += alpha * pw8[q]; r8[q] -= alpha * w8[q]; }
        cheb(r8, z8, dv8);
        double rzn_loc = 0.0;
        #pragma unroll
        for (int q = 0; q < 8; ++q) rzn_loc += (double)r8[q] * z8[q];
        const double rzn = bred(rzn_loc, redB);
        const float beta = (float)(rzn / rz);
        const bool slow = (rzn > 0.9 * rz);
        rz = rzn;
        if (slow) { if (++stg >= 2) break; } else stg = 0;
        if (rz > stop) {
            v4 p0, p1;
            #pragma unroll
            for (int q = 0; q < 8; ++q) pw8[q] = z8[q] + beta * pw8[q];
            #pragma unroll
            for (int q = 0; q < 4; ++q) p0[q] = pw8[q];
            #pragma unroll
            for (int q = 0; q < 4; ++q) p1[q] = pw8[q + 4];
            *(v4*)&P[base] = p0; *(v4*)&P[base + 4] = p1;
        }
    }

    // ---- final u = s .* y (interior), dbc on boundary ----
    __syncthreads();
    #pragma unroll
    for (int q = 0; q < 8; ++q) {
        const int i = row, j = cb + q;
        float uv;
        if (i == 0 || i == 63 || j == 0 || j == 63) uv = embedf(db, i, j);
        else uv = sD[q] * y8[q];
        P[base + q] = uv;
    }
    __syncthreads();

    // ---- Neumann flux (clockwise) + de-mean, fp64 from fp32 u ----
    double v = 0.0;
    if (t < NBP) {
        const double Hi = 63.0;
        if (t == 0)        v = (double)a[0]  * 0.5 * (((double)P[0] - P[LDF]) + ((double)P[0] - P[1])) * Hi;
        else if (t <= 62)  v = (double)a[t]  * ((double)P[t] - P[LDF + t]) * Hi;
        else if (t == 63)  v = (double)a[63] * 0.5 * (((double)P[63] - P[LDF + 63]) + ((double)P[63] - P[62])) * Hi;
        else if (t <= 125) { const int i = t - 63;
                             v = (double)a[(i<<6)+63] * ((double)P[i*LDF+63] - P[i*LDF+62]) * Hi; }
        else if (t == 126) v = (double)a[4095] * 0.5 * (((double)P[63*LDF+63] - P[62*LDF+63]) + ((double)P[63*LDF+63] - P[63*LDF+62])) * Hi;
        else if (t <= 188) { const int j = 189 - t;
                             v = (double)a[4032+j] * ((double)P[63*LDF+j] - P[62*LDF+j]) * Hi; }
        else if (t == 189) v = (double)a[4032] * 0.5 * (((double)P[63*LDF] - P[62*LDF]) + ((double)P[63*LDF] - P[63*LDF+1])) * Hi;
        else               { const int i = 252 - t;
                             v = (double)a[i<<6] * ((double)P[i*LDF] - P[i*LDF+1]) * Hi; }
    }
    const double tot = bred(v, redA);
    if (t < NBP) out[blockIdx.x * NBP + t] = (float)(v - tot * (1.0 / 252.0));
}

extern "C" void kernel_launch(void* const* d_in, const int* in_sizes, int n_in,
                              void* d_out, int out_size, void* d_ws, size_t ws_size,
                              hipStream_t stream) {
    const float* dbc = (const float*)d_in[0];   // (32, 252)
    const float* a   = (const float*)d_in[1];   // (64, 64)
    float* out = (float*)d_out;                 // (32, 252)
    dtn_cheb<<<dim3(32), dim3(BLK), 0, stream>>>(dbc, a, out);
}

// Round 5
// 91.342 us; speedup vs baseline: 3.3431x; 1.0296x over previous
//
#include <hip/hip_runtime.h>

// DtN operator, M=64, N=32 RHS. One workgroup per RHS.
// Chebyshev(deg-4)-preconditioned CG in fp32 (fp64 scalar accumulation) on the
// symmetrically scaled interior operator B = D^{-1/2} A D^{-1/2}.
// Thread t owns row t>>3, cols 8*(t&7)..+7. LDS rows stride 68 floats
// (16B-aligned float4 runs, bank-group (r+2c)%8 uniform -> b128 at bank floor).
// E/W neighbors come from lane+-1 registers via shuffles (boundary cases are
// zero-coefficient-masked; all live shuffles stay within a wave).

#define BLK 512
#define NBP 252
#define DEG 4
#define MAXOUT 35
#define LDF 68

typedef float v4 __attribute__((ext_vector_type(4)));

static __device__ __forceinline__ float hmf(float x, float y) {
    float d = x + y;
    return d == 0.f ? 0.f : 2.f * x * y / d;
}

// one-barrier block reduction, fp64
static __device__ __forceinline__ double bred(double v, double* slot) {
    #pragma unroll
    for (int off = 32; off > 0; off >>= 1) v += __shfl_down(v, off, 64);
    if ((threadIdx.x & 63) == 0) slot[threadIdx.x >> 6] = v;
    __syncthreads();
    double s = 0.0;
    #pragma unroll
    for (int w = 0; w < 8; ++w) s += slot[w];
    return s;
}

// clockwise Dirichlet embedding (top, right, bottom rev, left rev)
static __device__ __forceinline__ float embedf(const float* db, int i, int j) {
    if (i == 0 && j <= 62) return db[j];
    if (j == 63 && i <= 62) return db[63 + i];
    if (i == 63 && j >= 1)  return db[189 - j];
    return db[252 - i];   // j==0, i>=1
}

__global__ __launch_bounds__(BLK, 1) void dtn_cheb(const float* __restrict__ dbc,
                                                   const float* __restrict__ a,
                                                   float* __restrict__ out) {
    __shared__ float P[64 * LDF];
    __shared__ float Z0[64 * LDF];
    __shared__ float Z1[64 * LDF];
    __shared__ double redA[8], redB[8];

    const int t = threadIdx.x;
    const int row = t >> 3;
    const int cb  = (t & 7) << 3;
    const int gbase = (row << 6) + cb;
    const int base  = row * LDF + cb;
    const float* db = dbc + blockIdx.x * NBP;
    const bool irow = (row >= 1 && row <= 62);

    // zero-fill (pads must be 0: edge reads hit them, x0 coefficients)
    for (int i = t; i < 64 * LDF; i += BLK) { P[i] = 0.f; Z0[i] = 0.f; Z1[i] = 0.f; }
    __syncthreads();

    float cE[8], cW[8], cN[8], cS[8], sD[8];
    float r8[8], y8[8], z8[8], dv8[8], pw8[8];

    // ---- coefficients (h^-2 cancels), diag scale s, u0 embed ----
    #pragma unroll
    for (int q = 0; q < 8; ++q) {
        const int gi = gbase + q;
        const int i = row, j = cb + q;
        float e = 0, w = 0, nn = 0, ss = 0, sv = 0;
        if (i > 0 && i < 63 && j > 0 && j < 63) {
            const float ac = a[gi];
            e  = hmf(ac, a[gi + 1]);
            w  = hmf(a[gi - 1], ac);
            nn = hmf(a[gi - 64], ac);
            ss = hmf(ac, a[gi + 64]);
            sv = 1.f / sqrtf(e + w + nn + ss);
        }
        cE[q] = e; cW[q] = w; cN[q] = nn; cS[q] = ss; sD[q] = sv;
        float uv = 0.f;
        if (i == 0 || i == 63 || j == 0 || j == 63) uv = embedf(db, i, j);
        P[base + q]  = uv;
        Z0[base + q] = sv;
        y8[q] = 0.f; r8[q] = 0.f;
    }
    __syncthreads();

    // ---- r0 = s .* (A_raw u0); scale coefficients by s_i * s_neighbor ----
    if (irow) {
        #pragma unroll
        for (int q = 0; q < 8; ++q) {
            const int idx = base + q;
            r8[q] = sD[q] * (cE[q] * P[idx + 1] + cW[q] * P[idx - 1] +
                             cN[q] * P[idx - LDF] + cS[q] * P[idx + LDF]);
            cE[q] *= sD[q] * Z0[idx + 1];
            cW[q] *= sD[q] * Z0[idx - 1];
            cN[q] *= sD[q] * Z0[idx - LDF];
            cS[q] *= sD[q] * Z0[idx + LDF];
        }
    } else {
        #pragma unroll
        for (int q = 0; q < 8; ++q) { cE[q] = cW[q] = cN[q] = cS[q] = 0.f; }
    }
    __syncthreads();   // Z0 (s) reads done before cheb reuses it

    // ---- Chebyshev preconditioner on [0.02, 2.0] ----
    const float thet = 1.01f, delt = 0.99f;
    const float sigc = thet / delt;
    const float invthet = 1.f / thet;

    auto cheb = [&](const float* rr, float* zz, float* dv) {
        float rho = 1.f / sigc;
        {
            v4 a0, a1;
            #pragma unroll
            for (int q = 0; q < 4; ++q) { dv[q] = rr[q] * invthet; zz[q] = dv[q]; a0[q] = dv[q]; }
            #pragma unroll
            for (int q = 4; q < 8; ++q) { dv[q] = rr[q] * invthet; zz[q] = dv[q]; a1[q - 4] = dv[q]; }
            *(v4*)&Z1[base] = a0; *(v4*)&Z1[base + 4] = a1;
        }
        int cur = 1;
        for (int k = 2; k <= DEG; ++k) {
            __syncthreads();
            // E/W neighbors live in lane+-1 registers (lockstep-current);
            // wave-boundary / row-crossing pulls are zero-coef-masked.
            const float wv = __shfl_up(zz[7], 1);
            const float ev = __shfl_down(zz[0], 1);
            const float* Zc = cur ? Z1 : Z0;
            float res[8];
            if (irow) {
                const v4 n0 = *(const v4*)&Zc[base - LDF], n1 = *(const v4*)&Zc[base - LDF + 4];
                const v4 s0 = *(const v4*)&Zc[base + LDF], s1 = *(const v4*)&Zc[base + LDF + 4];
                const float vN[8] = {n0[0],n0[1],n0[2],n0[3],n1[0],n1[1],n1[2],n1[3]};
                const float vS[8] = {s0[0],s0[1],s0[2],s0[3],s1[0],s1[1],s1[2],s1[3]};
                #pragma unroll
                for (int q = 0; q < 8; ++q) {
                    const float vW = (q == 0) ? wv : zz[q - 1];
                    const float vE = (q == 7) ? ev : zz[q + 1];
                    res[q] = rr[q] - (zz[q] - (cE[q] * vE + cW[q] * vW +
                                               cN[q] * vN[q] + cS[q] * vS[q]));
                }
            } else {
                #pragma unroll
                for (int q = 0; q < 8; ++q) res[q] = 0.f;
            }
            const float rho1 = 1.f / (2.f * sigc - rho);
            const float c1 = rho1 * rho, c2 = 2.f * rho1 / delt;
            v4 a0, a1;
            #pragma unroll
            for (int q = 0; q < 8; ++q) { dv[q] = c1 * dv[q] + c2 * res[q]; zz[q] += dv[q]; }
            #pragma unroll
            for (int q = 0; q < 4; ++q) a0[q] = zz[q];
            #pragma unroll
            for (int q = 0; q < 4; ++q) a1[q] = zz[q + 4];
            if (cur) { *(v4*)&Z0[base] = a0; *(v4*)&Z0[base + 4] = a1; }
            else     { *(v4*)&Z1[base] = a0; *(v4*)&Z1[base + 4] = a1; }
            rho = rho1; cur ^= 1;
        }
    };

    // ---- PCG on B y = r0 ----
    cheb(r8, z8, dv8);
    double rz_loc = 0.0;
    #pragma unroll
    for (int q = 0; q < 8; ++q) { pw8[q] = z8[q]; rz_loc += (double)r8[q] * z8[q]; }
    {
        v4 p0, p1;
        #pragma unroll
        for (int q = 0; q < 4; ++q) p0[q] = pw8[q];
        #pragma unroll
        for (int q = 0; q < 4; ++q) p1[q] = pw8[q + 4];
        *(v4*)&P[base] = p0; *(v4*)&P[base + 4] = p1;
    }
    double rz = bred(rz_loc, redB);
    const double stop = rz * 1e-7;
    int stg = 0;

    for (int ot = 0; ot < MAXOUT && rz > stop; ++ot) {
        __syncthreads();   // p writes visible
        float w8[8];
        double pap_loc = 0.0;
        const float wv = __shfl_up(pw8[7], 1);
        const float ev = __shfl_down(pw8[0], 1);
        if (irow) {
            const v4 n0 = *(const v4*)&P[base - LDF], n1 = *(const v4*)&P[base - LDF + 4];
            const v4 s0 = *(const v4*)&P[base + LDF], s1 = *(const v4*)&P[base + LDF + 4];
            const float vN[8] = {n0[0],n0[1],n0[2],n0[3],n1[0],n1[1],n1[2],n1[3]};
            const float vS[8] = {s0[0],s0[1],s0[2],s0[3],s1[0],s1[1],s1[2],s1[3]};
            #pragma unroll
            for (int q = 0; q < 8; ++q) {
                const float vW = (q == 0) ? wv : pw8[q - 1];
                const float vE = (q == 7) ? ev : pw8[q + 1];
                w8[q] = pw8[q] - (cE[q] * vE + cW[q] * vW + cN[q] * vN[q] + cS[q] * vS[q]);
                pap_loc += (double)pw8[q] * w8[q];
            }
        } else {
            #pragma unroll
            for (int q = 0; q < 8; ++q) w8[q] = 0.f;
        }
        const double pap = bred(pap_loc, redA);
        if (!(pap > 0.0)) break;
        const float alpha = (float)(rz / pap);
        #pragma unroll
        for (int q = 0; q < 8; ++q) { y8[q] += alpha * pw8[q]; r8[q] -= alpha * w8[q]; }
        cheb(r8, z8, dv8);
        double rzn_loc = 0.0;
        #pragma unroll
        for (int q = 0; q < 8; ++q) rzn_loc += (double)r8[q] * z8[q];
        const double rzn = bred(rzn_loc, redB);
        const float beta = (float)(rzn / rz);
        const bool slow = (rzn > 0.9 * rz);
        rz = rzn;
        if (slow) { if (++stg >= 2) break; } else stg = 0;
        if (rz > stop) {
            v4 p0, p1;
            #pragma unroll
            for (int q = 0; q < 8; ++q) pw8[q] = z8[q] + beta * pw8[q];
            #pragma unroll
            for (int q = 0; q < 4; ++q) p0[q] = pw8[q];
            #pragma unroll
            for (int q = 0; q < 4; ++q) p1[q] = pw8[q + 4];
            *(v4*)&P[base] = p0; *(v4*)&P[base + 4] = p1;
        }
    }

    // ---- final u = s .* y (interior), dbc on boundary ----
    __syncthreads();
    #pragma unroll
    for (int q = 0; q < 8; ++q) {
        const int i = row, j = cb + q;
        float uv;
        if (i == 0 || i == 63 || j == 0 || j == 63) uv = embedf(db, i, j);
        else uv = sD[q] * y8[q];
        P[base + q] = uv;
    }
    __syncthreads();

    // ---- Neumann flux (clockwise) + de-mean, fp64 from fp32 u ----
    double v = 0.0;
    if (t < NBP) {
        const double Hi = 63.0;
        if (t == 0)        v = (double)a[0]  * 0.5 * (((double)P[0] - P[LDF]) + ((double)P[0] - P[1])) * Hi;
        else if (t <= 62)  v = (double)a[t]  * ((double)P[t] - P[LDF + t]) * Hi;
        else if (t == 63)  v = (double)a[63] * 0.5 * (((double)P[63] - P[LDF + 63]) + ((double)P[63] - P[62])) * Hi;
        else if (t <= 125) { const int i = t - 63;
                             v = (double)a[(i<<6)+63] * ((double)P[i*LDF+63] - P[i*LDF+62]) * Hi; }
        else if (t == 126) v = (double)a[4095] * 0.5 * (((double)P[63*LDF+63] - P[62*LDF+63]) + ((double)P[63*LDF+63] - P[63*LDF+62])) * Hi;
        else if (t <= 188) { const int j = 189 - t;
                             v = (double)a[4032+j] * ((double)P[63*LDF+j] - P[62*LDF+j]) * Hi; }
        else if (t == 189) v = (double)a[4032] * 0.5 * (((double)P[63*LDF] - P[62*LDF]) + ((double)P[63*LDF] - P[63*LDF+1])) * Hi;
        else               { const int i = 252 - t;
                             v = (double)a[i<<6] * ((double)P[i*LDF] - P[i*LDF+1]) * Hi; }
    }
    const double tot = bred(v, redA);
    if (t < NBP) out[blockIdx.x * NBP + t] = (float)(v - tot * (1.0 / 252.0));
}

extern "C" void kernel_launch(void* const* d_in, const int* in_sizes, int n_in,
                              void* d_out, int out_size, void* d_ws, size_t ws_size,
                              hipStream_t stream) {
    const float* dbc = (const float*)d_in[0];   // (32, 252)
    const float* a   = (const float*)d_in[1];   // (64, 64)
    float* out = (float*)d_out;                 // (32, 252)
    dtn_cheb<<<dim3(32), dim3(BLK), 0, stream>>>(dbc, a, out);
}